// Round 8
// baseline (1050.385 us; speedup 1.0000x reference)
//
#include <hip/hip_runtime.h>
#include <stdint.h>

#define D 128
#define TN 160000
#define NSUB 3200
#define GG 64
#define NL 4

typedef __bf16 bf16x8 __attribute__((ext_vector_type(8)));
typedef float f32x4 __attribute__((ext_vector_type(4)));
typedef unsigned int u32x4 __attribute__((ext_vector_type(4)));

__device__ __forceinline__ unsigned short f2bf(float v) {
    union { float f; uint32_t u; } c; c.f = v;
    uint32_t r = c.u + 0x7fffu + ((c.u >> 16) & 1u);
    return (unsigned short)(r >> 16);
}
__device__ __forceinline__ float bf2f(unsigned short h) {
    union { float f; uint32_t u; } c; c.u = ((uint32_t)h) << 16;
    return c.f;
}

__device__ __forceinline__ void gload16(const void* g, void* l) {
    __builtin_amdgcn_global_load_lds(
        (const __attribute__((address_space(1))) unsigned int*)g,
        (__attribute__((address_space(3))) unsigned int*)l, 16, 0, 0);
}

// ---------------------------------------------------------------------------
// Fused GraphConv via MFMA. Block = 2 units (100 rows) x 256 cols.
// A3: [M][256] bf16 = [hi|lo] of x, staged ONCE (source-XOR-swizzled; frag
// reads apply the same XOR). B staged tile-by-tile (16KB) via global_load_lds;
// fragments read to registers, then buffer re-staged with tile t+1 while
// tile t's MFMAs run. Virtual K = 384: hi*Whi + lo*Whi + hi*Wlo.
// Epilogue v2 (divergence-free): two column-halves; per half, one wave dumps
// Yr and one dumps Yn into LDS (overlaying dead A/B), then each wave owns
// 25 dst rows x 64 cols: wave-UNIFORM CSR edge loop, consecutive-lane LDS
// reads (2-way alias = free), 256B-contiguous H stores, BN stats fused.
// ---------------------------------------------------------------------------
__global__ __launch_bounds__(256, 2)
void gconv_kernel(const unsigned short* __restrict__ A3,
                  const unsigned short* __restrict__ Wt,
                  const float* __restrict__ bias,
                  const int* __restrict__ rp,
                  const unsigned char* __restrict__ colx,
                  float* __restrict__ H,
                  float* __restrict__ stats)
{
    __shared__ __align__(16) char lds[68800];
    unsigned short* Blds = (unsigned short*)(lds + 51200);  // [256n][32k], 16KB
    float* aggN = (float*)lds;                              // [100][66] overlay
    float* aggR = (float*)(lds + 26400);                    // [100][66] overlay
    int* rpl = (int*)(lds + 67584);                         // 102 ints
    unsigned char* coll = (unsigned char*)(lds + 67992);    // 800B

    const int tid = threadIdx.x;
    const int blk = blockIdx.x;
    const int rowbase = blk * 100;
    const int lane = tid & 63, wv = tid >> 6;
    const int p = lane & 15, q = lane >> 4;
    const int wn0 = wv * 64;

    // ---- stage A once: 3200 granules of 16B, source-swizzled ----
#pragma unroll
    for (int i = 0; i < 12; ++i) {
        const int c = i * 256 + tid;
        const int r = c >> 5, g = c & 31;
        gload16(A3 + (size_t)(rowbase + r) * 256 + ((g ^ (r & 7)) << 3),
                lds + ((i * 256 + (wv << 6)) << 4));
    }
    if (wv < 2) {
        const int c = 3072 + (wv << 6) + lane;
        const int r = c >> 5, g = c & 31;
        gload16(A3 + (size_t)(rowbase + r) * 256 + ((g ^ (r & 7)) << 3),
                lds + ((3072 + (wv << 6)) << 4));
    }
    // ---- stage B tile 0 ----
#pragma unroll
    for (int rr = 0; rr < 4; ++rr) {
        const int cb = rr * 256 + (wv << 6);
        gload16(Wt + (size_t)(cb + lane) * 8, Blds + cb * 8);
    }
    if (tid < 102) rpl[tid] = rp[blk * 102 + tid];
    if (tid < 200)
        ((uint32_t*)coll)[tid] = ((const uint32_t*)(colx + (size_t)blk * 800))[tid];

    f32x4 acc[7][4];
#pragma unroll
    for (int i = 0; i < 7; ++i)
#pragma unroll
        for (int j = 0; j < 4; ++j) acc[i][j] = (f32x4){0.f, 0.f, 0.f, 0.f};

    __syncthreads();   // A + B0 + metadata ready

    // ---- K-loop: 8 B-tiles, frags->regs then re-stage the single buffer ----
    static const int MROW[7] = {0, 16, 32, 48, 64, 80, 84};
    bf16x8 bfr[4];
#pragma unroll
    for (int t = 0; t < 8; ++t) {
#pragma unroll
        for (int ni = 0; ni < 4; ++ni) {
            u32x4 raw = *(const u32x4*)&Blds[(wn0 + ni * 16 + p) * 32 + q * 8];
            bfr[ni] = __builtin_bit_cast(bf16x8, raw);
        }
        __syncthreads();               // all waves hold frags; buffer reusable
        if (t < 7) {
#pragma unroll
            for (int rr = 0; rr < 4; ++rr) {
                const int cb = rr * 256 + (wv << 6);
                gload16(Wt + ((size_t)(t + 1) << 13) + (size_t)(cb + lane) * 8,
                        Blds + cb * 8);
            }
        }
        const int na = (t < 4) ? 2 : 1;
        for (int a = 0; a < na; ++a) {
            const int ka = (t < 4) ? (t * 32 + a * 128) : ((t - 4) * 32);
            const int gbase = (ka >> 3) + q;
#pragma unroll
            for (int mi = 0; mi < 7; ++mi) {
                const int r = MROW[mi] + p;
                u32x4 raw = *(const u32x4*)(lds + r * 512 + ((gbase ^ (r & 7)) << 4));
                bf16x8 afr = __builtin_bit_cast(bf16x8, raw);
#pragma unroll
                for (int ni = 0; ni < 4; ++ni)
                    acc[mi][ni] = __builtin_amdgcn_mfma_f32_16x16x32_bf16(afr, bfr[ni], acc[mi][ni], 0, 0, 0);
            }
        }
        __syncthreads();               // stage t+1 drained; compute done
    }

    // ---- epilogue v2: two column-halves, wave-uniform aggregation ----
    for (int hf = 0; hf < 2; ++hf) {
        // dump: wave hf -> aggR (Yr cols hf*64..), wave 2+hf -> aggN
        if (wv == hf || wv == 2 + hf) {
            float* dbuf = (wv >= 2) ? aggN : aggR;
#pragma unroll
            for (int mi = 0; mi < 7; ++mi)
#pragma unroll
                for (int r = 0; r < 4; ++r) {
                    const int row = MROW[mi] + q * 4 + r;
                    if (mi == 6 && row < 96) continue;
#pragma unroll
                    for (int ni = 0; ni < 4; ++ni)
                        dbuf[row * 66 + ni * 16 + p] = acc[mi][ni][r];
                }
        }
        __syncthreads();
        // compute: wave wv owns rows wv*25..wv*25+24; lane = local col
        {
            const int cg = hf * 64 + lane;
            const int r0 = wv * 25;
            const int ul = (r0 >= 50) ? 1 : 0;
            const float bv = bias[cg];
            float sm = 0.f, sq = 0.f;
            for (int d = 0; d < 25; ++d) {
                const int row = r0 + d;
                const int dl = row - ul * 50;
                const int e0 = rpl[ul * 51 + dl], e1 = rpl[ul * 51 + dl + 1];
                float s = aggR[row * 66 + lane] + bv;
                for (int e = e0; e < e1; ++e)
                    s += aggN[((int)coll[ul * 400 + e] + ul * 50) * 66 + lane];
                H[(size_t)(rowbase + row) * 128 + cg] = s;
                sm += s; sq += s * s;
            }
            float* rep = stats + (size_t)(blk & 63) * 256;
            atomicAdd(&rep[cg], sm);
            atomicAdd(&rep[128 + cg], sq);
        }
        __syncthreads();   // buffers reusable for next half
    }
}

// ---------------------------------------------------------------------------
// fuse (BN1+BN2[node_idx]+relu) + bf16 split -> A3, and subgraph-mean -> XS.
// One block per original node (g,n): 50 subgraph-copy rows x 128 ch.
// ---------------------------------------------------------------------------
template <bool FUSE>
__global__ __launch_bounds__(256)
void fusexsum_kernel(const float* __restrict__ HP,
                     const float* __restrict__ H2,
                     const float* __restrict__ prm,
                     unsigned short* __restrict__ A3,
                     unsigned short* __restrict__ XS)
{
    __shared__ float red[256];
    const int blk = blockIdx.x;          // g*50 + n
    const int g = blk / 50, n = blk - g * 50;
    const int tid = threadIdx.x;
    const int c = tid & 127, sh = tid >> 7;
    float a1 = 0.f, c1 = 0.f, hh = 0.f;
    if (FUSE) {
        a1 = prm[c]; c1 = prm[128 + c];
        const float a2 = prm[256 + c], c2 = prm[384 + c];
        hh = a2 * H2[(size_t)blk * 128 + c] + c2;
    }
    float accum = 0.f;
    const int s0 = sh * 25;
    for (int s = s0; s < s0 + 25; ++s) {
        const size_t row = (size_t)g * 2500 + s * 50 + n;
        float v = HP[row * 128 + c];
        if (FUSE) v = fmaxf(0.f, a1 * v + c1 + hh);
        const unsigned short hi = f2bf(v);
        const unsigned short lo = f2bf(v - bf2f(hi));
        A3[row * 256 + c] = hi;
        A3[row * 256 + 128 + c] = lo;
        accum += v;
    }
    red[tid] = accum;
    __syncthreads();
    if (tid < 128) {
        const float xv = (red[tid] + red[tid + 128]) * 0.02f;
        const unsigned short hi = f2bf(xv);
        const unsigned short lo = f2bf(xv - bf2f(hi));
        XS[(size_t)blk * 256 + c] = hi;
        XS[(size_t)blk * 256 + 128 + c] = lo;
    }
}

// per-unit CSR build: 50 nodes, 400 edges, all endpoints inside the unit
__global__ void csr_build(const int* __restrict__ src, const int* __restrict__ dst,
                          int* __restrict__ rp, unsigned char* __restrict__ colx)
{
    __shared__ int cnt[50];
    __shared__ int base[51];
    __shared__ short dl[400], sl[400];
    const int u = blockIdx.x, t = threadIdx.x;   // 64 threads
    if (t < 50) cnt[t] = 0;
    __syncthreads();
    for (int e = t; e < 400; e += 64) {
        const int dd = dst[u * 400 + e] - u * 50;
        const int ss = src[u * 400 + e] - u * 50;
        dl[e] = (short)dd; sl[e] = (short)ss;
        atomicAdd(&cnt[dd], 1);
    }
    __syncthreads();
    if (t == 0) {
        int s = 0;
        for (int i = 0; i < 50; ++i) { base[i] = s; s += cnt[i]; }
        base[50] = 400;
    }
    __syncthreads();
    if (t < 51) rp[u * 51 + t] = base[t];
    if (t < 50) cnt[t] = base[t];
    __syncthreads();
    for (int e = t; e < 400; e += 64) {
        const int pos = atomicAdd(&cnt[dl[e]], 1);
        colx[u * 400 + pos] = (unsigned char)sl[e];
    }
}

// build W3T: 8 matrices x 8 tiles x [256 n][32 k] bf16; tiles 0-3 hi, 4-7 lo
__global__ void w3t_kernel(const float* __restrict__ Wr, const float* __restrict__ Wn,
                           const float* __restrict__ Wsr, const float* __restrict__ Wsn,
                           unsigned short* __restrict__ W3T)
{
    const int idx = blockIdx.x * 256 + threadIdx.x;  // 8*65536
    const int m = idx >> 16;
    const int r = idx & 65535;
    const int bt = r >> 13;
    const int rr = r & 8191;
    const int n = rr >> 5, kloc = rr & 31;
    const int kg = (bt & 3) * 32 + kloc;
    const float* Wa = (m < 4) ? Wr + (size_t)m * 16384 : Wsr + (size_t)(m - 4) * 16384;
    const float* Wb = (m < 4) ? Wn + (size_t)m * 16384 : Wsn + (size_t)(m - 4) * 16384;
    const float w = (n < 128) ? Wa[kg * 128 + n] : Wb[kg * 128 + (n - 128)];
    const unsigned short hi = f2bf(w);
    W3T[idx] = (bt < 4) ? hi : f2bf(w - bf2f(hi));
}

// finalize BN params from 64-replica stats; prm = [a1,c1,a2,c2]; re-zero reps
__global__ void bnfin_kernel(float* __restrict__ stats,
                             const float* __restrict__ bng, const float* __restrict__ bnb,
                             const float* __restrict__ bnsg, const float* __restrict__ bnsb,
                             float* __restrict__ prm)
{
    __shared__ float sN[256], sS[256];
    const int tid = threadIdx.x;
    float aN = 0.f, aS = 0.f;
    for (int r = 0; r < 64; ++r) {
        aN += stats[r * 256 + tid];
        aS += stats[16384 + r * 256 + tid];
    }
    sN[tid] = aN; sS[tid] = aS;
    __syncthreads();
    if (tid < 128) {
        const float mu = sN[tid] / (float)TN;
        const float var = sN[128 + tid] / (float)TN - mu * mu;
        const float a = bng[tid] / sqrtf(var + 1e-5f);
        prm[tid] = a;
        prm[128 + tid] = bnb[tid] - mu * a;
    } else {
        const int c = tid - 128;
        const float mu = sS[c] / (float)NSUB;
        const float var = sS[128 + c] / (float)NSUB - mu * mu;
        const float a = bnsg[c] / sqrtf(var + 1e-5f);
        prm[256 + c] = a;
        prm[384 + c] = bnsb[c] - mu * a;
    }
    for (int i = tid; i < 32768; i += 256) stats[i] = 0.f;
}

// graph pooling from XS: mean over n
__global__ void pool_kernel(const unsigned short* __restrict__ XS, float* __restrict__ hg)
{
    const int g = blockIdx.x, c = threadIdx.x;   // 128 threads
    float s = 0.f;
    for (int n = 0; n < 50; ++n) {
        const unsigned short* pp = XS + (size_t)(g * 50 + n) * 256;
        s += bf2f(pp[c]) + bf2f(pp[128 + c]);
    }
    hg[g * 128 + c] = s * 0.02f;
}

__global__ void mlp_kernel(const float* __restrict__ hg,
                           const float* __restrict__ W1, const float* __restrict__ b1,
                           const float* __restrict__ W2, const float* __restrict__ b2,
                           float* __restrict__ out)
{
    __shared__ float xv[128];
    __shared__ float hid[256];
    const int g = blockIdx.x, tid = threadIdx.x;
    if (tid < 128) xv[tid] = hg[g * 128 + tid];
    __syncthreads();
    float a = b1[tid];
    for (int k = 0; k < 128; ++k) a += xv[k] * W1[k * 256 + tid];
    hid[tid] = fmaxf(a, 0.f);
    __syncthreads();
    if (tid < 10) {
        float o = b2[tid];
        for (int k = 0; k < 256; ++k) o += hid[k] * W2[k * 10 + tid];
        out[g * 10 + tid] = o;
    }
}

__global__ void zero_kernel(float* __restrict__ pz, int n)
{
    const int t = blockIdx.x * 256 + threadIdx.x;
    if (t < n) pz[t] = 0.f;
}

extern "C" void kernel_launch(void* const* d_in, const int* in_sizes, int n_in,
                              void* d_out, int out_size, void* d_ws, size_t ws_size,
                              hipStream_t stream)
{
    const float* x0   = (const float*)d_in[0];
    const float* Wr   = (const float*)d_in[1];
    const float* Wn   = (const float*)d_in[2];
    const float* bb   = (const float*)d_in[3];
    const float* bng  = (const float*)d_in[4];
    const float* bnb  = (const float*)d_in[5];
    const float* Wsr  = (const float*)d_in[6];
    const float* Wsn  = (const float*)d_in[7];
    const float* bs   = (const float*)d_in[8];
    const float* bnsg = (const float*)d_in[9];
    const float* bnsb = (const float*)d_in[10];
    const float* fW1  = (const float*)d_in[11];
    const float* fb1  = (const float*)d_in[12];
    const float* fW2  = (const float*)d_in[13];
    const float* fb2  = (const float*)d_in[14];
    const int* ei     = (const int*)d_in[15];
    const int* oei    = (const int*)d_in[16];
    float* out        = (float*)d_out;

    char* w = (char*)d_ws;
    unsigned short* A3  = (unsigned short*)w; w += (size_t)TN * 256 * 2;
    float* H1           = (float*)w;          w += (size_t)TN * 128 * 4;
    unsigned short* W3T = (unsigned short*)w; w += (size_t)8 * 65536 * 2;
    unsigned short* XS  = (unsigned short*)w; w += (size_t)NSUB * 256 * 2;
    float* H2           = (float*)w;          w += (size_t)NSUB * 128 * 4;
    int* rps            = (int*)w;            w += (size_t)NSUB * 51 * 4;
    unsigned char* cls  = (unsigned char*)w;  w += (size_t)NSUB * 400;
    int* rpo            = (int*)w;            w += (size_t)GG * 51 * 4;
    unsigned char* clo  = (unsigned char*)w;  w += (size_t)GG * 400;
    float* stats        = (float*)w;          w += (size_t)32768 * 4;  // [2][64][256]
    float* prm          = (float*)w;          w += 512 * 4;
    float* hg           = (float*)w;          w += (size_t)GG * 128 * 4;

    w3t_kernel<<<2048, 256, 0, stream>>>(Wr, Wn, Wsr, Wsn, W3T);
    csr_build<<<NSUB, 64, 0, stream>>>(ei, ei + 1280000, rps, cls);
    csr_build<<<GG, 64, 0, stream>>>(oei, oei + 25600, rpo, clo);
    zero_kernel<<<128, 256, 0, stream>>>(stats, 32768);
    fusexsum_kernel<false><<<NSUB, 256, 0, stream>>>(x0, nullptr, nullptr, A3, XS);

    for (int i = 0; i < NL; ++i) {
        gconv_kernel<<<TN / 100, 256, 0, stream>>>(A3, W3T + (size_t)i * 65536,
                                                   bb + i * 128, rps, cls, H1, stats);
        gconv_kernel<<<NSUB / 100, 256, 0, stream>>>(XS, W3T + (size_t)(4 + i) * 65536,
                                                     bs + i * 128, rpo, clo, H2, stats + 16384);
        bnfin_kernel<<<1, 256, 0, stream>>>(stats, bng + i * 128, bnb + i * 128,
                                            bnsg + i * 128, bnsb + i * 128, prm);
        fusexsum_kernel<true><<<NSUB, 256, 0, stream>>>(H1, H2, prm, A3, XS);
    }

    pool_kernel<<<GG, 128, 0, stream>>>(XS, hg);
    mlp_kernel<<<GG, 256, 0, stream>>>(hg, fW1, fb1, fW2, fb2, out);
}

// Round 9
// 793.324 us; speedup vs baseline: 1.3240x; 1.3240x over previous
//
#include <hip/hip_runtime.h>
#include <stdint.h>

#define D 128
#define TN 160000
#define NSUB 3200
#define GG 64
#define NL 4

typedef __bf16 bf16x8 __attribute__((ext_vector_type(8)));
typedef float f32x4 __attribute__((ext_vector_type(4)));
typedef unsigned int u32x4 __attribute__((ext_vector_type(4)));

__device__ __forceinline__ unsigned short f2bf(float v) {
    union { float f; uint32_t u; } c; c.f = v;
    uint32_t r = c.u + 0x7fffu + ((c.u >> 16) & 1u);
    return (unsigned short)(r >> 16);
}
__device__ __forceinline__ float bf2f(unsigned short h) {
    union { float f; uint32_t u; } c; c.u = ((uint32_t)h) << 16;
    return c.f;
}

__device__ __forceinline__ void gload16(const void* g, void* l) {
    __builtin_amdgcn_global_load_lds(
        (const __attribute__((address_space(1))) unsigned int*)g,
        (__attribute__((address_space(3))) unsigned int*)l, 16, 0, 0);
}

// ---------------------------------------------------------------------------
// Fused GraphConv via MFMA, 2-term precision: y = x_hi * (Whi + Wlo).
// Block = 2 units (100 rows) x 256 cols. A: [M][128] bf16 (hi only), staged
// ONCE into LDS (source-XOR-swizzled granules; frag reads apply same XOR).
// B: 8 tiles [256n][32k]; each wave stages ITS OWN 64-col slice (4KB/tile)
// into a wave-private ping-pong pair via global_load_lds, synced with
// wave-local s_waitcnt vmcnt(0) -- ZERO block barriers in the K-loop.
// K-loop: 8 tile-steps x {4 B-frag ds_reads + 7 A-frag ds_reads + 28 MFMA},
// s_setprio(1) around each MFMA cluster.
// Epilogue (r7-proven): Yn -> agg LDS (overlays A+B), per-row CSR aggregate,
// H = Yr+agg+bias -> global as bf16; BN stats -> 64-way replicated atomics.
// ---------------------------------------------------------------------------
__global__ __launch_bounds__(256, 2)
void gconv_kernel(const unsigned short* __restrict__ A3,
                  const unsigned short* __restrict__ Wt,
                  const float* __restrict__ bias,
                  const int* __restrict__ rp,
                  const unsigned char* __restrict__ colx,
                  unsigned short* __restrict__ H,
                  float* __restrict__ stats)
{
    __shared__ __align__(16) char lds[59576];
    // A: [100][128] shorts at lds+0 (25600 B), granule-swizzled
    // B: 4 waves x 2 bufs x 4096 B at lds+25600 (32768 B)
    // agg overlay: [100][130] f32 at lds+0 (52000 B, over dead A+B)
    float* agg = (float*)lds;
    int* rpl = (int*)(lds + 58368);                      // 102 ints
    unsigned char* coll = (unsigned char*)(lds + 58776); // 800 B

    const int tid = threadIdx.x;
    const int blk = blockIdx.x;
    const int rowbase = blk * 100;
    const int lane = tid & 63, wv = tid >> 6;
    const int p = lane & 15, q = lane >> 4;
    const int wn0 = wv * 64;

    // ---- stage A once: 1600 granules of 16B, source-swizzled ----
#pragma unroll
    for (int i = 0; i < 6; ++i) {
        const int c = i * 256 + tid;
        const int r = c >> 4, g = c & 15;
        gload16(A3 + (size_t)(rowbase + r) * 128 + ((g ^ (r & 7)) << 3),
                lds + ((i * 256 + (wv << 6)) << 4));
    }
    if (wv == 0) {
        const int c = 1536 + lane;
        const int r = c >> 4, g = c & 15;
        gload16(A3 + (size_t)(rowbase + r) * 128 + ((g ^ (r & 7)) << 3),
                lds + (1536 << 4));
    }
    // ---- stage B tile 0 into this wave's buf 0 ----
    {
        char* dst = lds + 25600 + ((wv * 2 + 0) << 12);
#pragma unroll
        for (int j = 0; j < 4; ++j)
            gload16(Wt + (size_t)wn0 * 32 + (size_t)(j * 64 + lane) * 8,
                    dst + (j << 10));
    }
    if (tid < 102) rpl[tid] = rp[blk * 102 + tid];
    if (tid < 200)
        ((uint32_t*)coll)[tid] = ((const uint32_t*)(colx + (size_t)blk * 800))[tid];

    f32x4 acc[7][4];
#pragma unroll
    for (int i = 0; i < 7; ++i)
#pragma unroll
        for (int j = 0; j < 4; ++j) acc[i][j] = (f32x4){0.f, 0.f, 0.f, 0.f};

    __syncthreads();   // A + B0 + metadata ready (drains all staging)

    // ---- K-loop: 8 tiles, wave-private B ping-pong, NO block barriers ----
    static const int MROW[7] = {0, 16, 32, 48, 64, 80, 84};
    const unsigned short* Ash = (const unsigned short*)lds;
#pragma unroll
    for (int t = 0; t < 8; ++t) {
        if (t > 0) asm volatile("s_waitcnt vmcnt(0)" ::: "memory");
        const unsigned short* Bw =
            (const unsigned short*)(lds + 25600 + ((wv * 2 + (t & 1)) << 12));
        bf16x8 bfr[4];
#pragma unroll
        for (int ni = 0; ni < 4; ++ni) {
            u32x4 raw = *(const u32x4*)&Bw[(ni * 16 + p) * 32 + q * 8];
            bfr[ni] = __builtin_bit_cast(bf16x8, raw);
        }
        if (t < 7) {   // stage next tile into the other private buf
            char* dst = lds + 25600 + ((wv * 2 + ((t + 1) & 1)) << 12);
#pragma unroll
            for (int j = 0; j < 4; ++j)
                gload16(Wt + ((size_t)(t + 1) << 13) + (size_t)wn0 * 32 +
                            (size_t)(j * 64 + lane) * 8,
                        dst + (j << 10));
        }
        const int gb = (t & 3) * 4 + q;
        __builtin_amdgcn_s_setprio(1);
#pragma unroll
        for (int mi = 0; mi < 7; ++mi) {
            const int r = MROW[mi] + p;
            u32x4 raw = *(const u32x4*)&Ash[r * 128 + ((gb ^ (r & 7)) << 3)];
            bf16x8 afr = __builtin_bit_cast(bf16x8, raw);
#pragma unroll
            for (int ni = 0; ni < 4; ++ni)
                acc[mi][ni] = __builtin_amdgcn_mfma_f32_16x16x32_bf16(afr, bfr[ni], acc[mi][ni], 0, 0, 0);
        }
        __builtin_amdgcn_s_setprio(0);
    }

    __syncthreads();   // all A/B reads done; region becomes agg

    // waves 2,3 hold Yn (GEMM cols 128:255): dump to agg
    if (wv >= 2) {
#pragma unroll
        for (int mi = 0; mi < 7; ++mi)
#pragma unroll
            for (int r = 0; r < 4; ++r) {
                const int row = MROW[mi] + q * 4 + r;
                if (mi == 6 && row < 96) continue;
#pragma unroll
                for (int ni = 0; ni < 4; ++ni)
                    agg[row * 130 + (wn0 - 128) + ni * 16 + p] = acc[mi][ni][r];
            }
    }
    __syncthreads();

    // waves 0,1 hold Yr (cols 0:127): CSR aggregate + bias, write H (bf16)
    if (wv < 2) {
        float bsv[4];
#pragma unroll
        for (int ni = 0; ni < 4; ++ni) bsv[ni] = bias[wn0 + ni * 16 + p];
#pragma unroll
        for (int mi = 0; mi < 7; ++mi)
#pragma unroll
            for (int r = 0; r < 4; ++r) {
                const int row = MROW[mi] + q * 4 + r;
                if (mi == 6 && row < 96) continue;
                const int ul = row >= 50 ? 1 : 0;
                const int dl = row - ul * 50;
                const int e0 = rpl[ul * 51 + dl], e1 = rpl[ul * 51 + dl + 1];
                float s0 = 0.f, s1 = 0.f, s2 = 0.f, s3 = 0.f;
                for (int e = e0; e < e1; ++e) {
                    const int sr = (int)coll[ul * 400 + e] + ul * 50;
                    s0 += agg[sr * 130 + wn0 + p];
                    s1 += agg[sr * 130 + wn0 + 16 + p];
                    s2 += agg[sr * 130 + wn0 + 32 + p];
                    s3 += agg[sr * 130 + wn0 + 48 + p];
                }
#pragma unroll
                for (int ni = 0; ni < 4; ++ni) {
                    const float sv = (ni == 0) ? s0 : (ni == 1) ? s1 : (ni == 2) ? s2 : s3;
                    const int cc = wn0 + ni * 16 + p;
                    const float h = acc[mi][ni][r] + sv + bsv[ni];
                    acc[mi][ni][r] = h;
                    H[(size_t)(rowbase + row) * 128 + cc] = f2bf(h);
                }
            }
    }
    __syncthreads();
    // waves 0,1 overwrite agg (own disjoint cols) with H for the stat reduce
    if (wv < 2) {
#pragma unroll
        for (int mi = 0; mi < 7; ++mi)
#pragma unroll
            for (int r = 0; r < 4; ++r) {
                const int row = MROW[mi] + q * 4 + r;
                if (mi == 6 && row < 96) continue;
#pragma unroll
                for (int ni = 0; ni < 4; ++ni)
                    agg[row * 130 + wn0 + ni * 16 + p] = acc[mi][ni][r];
            }
    }
    __syncthreads();
    // all 256 threads: stats partials -> replica (blk & 63)
    {
        const int c = tid & 127;
        const int r0 = (tid >> 7) * 50;
        float sm = 0.f, sq = 0.f;
        for (int r = r0; r < r0 + 50; ++r) {
            const float v = agg[r * 130 + c];
            sm += v; sq += v * v;
        }
        float* rep = stats + (size_t)(blk & 63) * 256;
        atomicAdd(&rep[c], sm);
        atomicAdd(&rep[128 + c], sq);
    }
}

// ---------------------------------------------------------------------------
// fuse (BN1+BN2[node_idx]+relu) + bf16 -> A3 (hi only), subgraph-mean -> XS.
// One block per original node (g,n): 50 subgraph-copy rows x 128 ch.
// FUSE: HP is bf16 H; else HP is fp32 x0 (layer 0).
// ---------------------------------------------------------------------------
template <bool FUSE>
__global__ __launch_bounds__(256)
void fusexsum_kernel(const void* __restrict__ HPv,
                     const unsigned short* __restrict__ H2,
                     const float* __restrict__ prm,
                     unsigned short* __restrict__ A3,
                     unsigned short* __restrict__ XS)
{
    __shared__ float red[256];
    const unsigned short* HPb = (const unsigned short*)HPv;
    const float* HPf = (const float*)HPv;
    const int blk = blockIdx.x;          // g*50 + n
    const int g = blk / 50, n = blk - g * 50;
    const int tid = threadIdx.x;
    const int c = tid & 127, sh = tid >> 7;
    float a1 = 0.f, c1 = 0.f, hh = 0.f;
    if (FUSE) {
        a1 = prm[c]; c1 = prm[128 + c];
        const float a2 = prm[256 + c], c2 = prm[384 + c];
        hh = a2 * bf2f(H2[(size_t)blk * 128 + c]) + c2;
    }
    float accum = 0.f;
    const int s0 = sh * 25;
    for (int s = s0; s < s0 + 25; ++s) {
        const size_t row = (size_t)g * 2500 + s * 50 + n;
        float v = FUSE ? bf2f(HPb[row * 128 + c]) : HPf[row * 128 + c];
        if (FUSE) v = fmaxf(0.f, a1 * v + c1 + hh);
        A3[row * 128 + c] = f2bf(v);
        accum += v;
    }
    red[tid] = accum;
    __syncthreads();
    if (tid < 128) {
        const float xv = (red[tid] + red[tid + 128]) * 0.02f;
        XS[(size_t)blk * 128 + c] = f2bf(xv);
    }
}

// per-unit CSR build: 50 nodes, 400 edges, all endpoints inside the unit
__global__ void csr_build(const int* __restrict__ src, const int* __restrict__ dst,
                          int* __restrict__ rp, unsigned char* __restrict__ colx)
{
    __shared__ int cnt[50];
    __shared__ int base[51];
    __shared__ short dl[400], sl[400];
    const int u = blockIdx.x, t = threadIdx.x;   // 64 threads
    if (t < 50) cnt[t] = 0;
    __syncthreads();
    for (int e = t; e < 400; e += 64) {
        const int dd = dst[u * 400 + e] - u * 50;
        const int ss = src[u * 400 + e] - u * 50;
        dl[e] = (short)dd; sl[e] = (short)ss;
        atomicAdd(&cnt[dd], 1);
    }
    __syncthreads();
    if (t == 0) {
        int s = 0;
        for (int i = 0; i < 50; ++i) { base[i] = s; s += cnt[i]; }
        base[50] = 400;
    }
    __syncthreads();
    if (t < 51) rp[u * 51 + t] = base[t];
    if (t < 50) cnt[t] = base[t];
    __syncthreads();
    for (int e = t; e < 400; e += 64) {
        const int pos = atomicAdd(&cnt[dl[e]], 1);
        colx[u * 400 + pos] = (unsigned char)sl[e];
    }
}

// build W3T: 8 matrices x 8 tiles x [256 n][32 k] bf16; tiles 0-3 = hi(W),
// tiles 4-7 = lo(W) k-slices. (2-term: both consumed with A-hi.)
__global__ void w3t_kernel(const float* __restrict__ Wr, const float* __restrict__ Wn,
                           const float* __restrict__ Wsr, const float* __restrict__ Wsn,
                           unsigned short* __restrict__ W3T)
{
    const int idx = blockIdx.x * 256 + threadIdx.x;  // 8*65536
    const int m = idx >> 16;
    const int r = idx & 65535;
    const int bt = r >> 13;
    const int rr = r & 8191;
    const int n = rr >> 5, kloc = rr & 31;
    const int kg = (bt & 3) * 32 + kloc;
    const float* Wa = (m < 4) ? Wr + (size_t)m * 16384 : Wsr + (size_t)(m - 4) * 16384;
    const float* Wb = (m < 4) ? Wn + (size_t)m * 16384 : Wsn + (size_t)(m - 4) * 16384;
    const float w = (n < 128) ? Wa[kg * 128 + n] : Wb[kg * 128 + (n - 128)];
    const unsigned short hi = f2bf(w);
    W3T[idx] = (bt < 4) ? hi : f2bf(w - bf2f(hi));
}

// finalize BN params from 64-replica stats; prm = [a1,c1,a2,c2]; re-zero reps
__global__ void bnfin_kernel(float* __restrict__ stats,
                             const float* __restrict__ bng, const float* __restrict__ bnb,
                             const float* __restrict__ bnsg, const float* __restrict__ bnsb,
                             float* __restrict__ prm)
{
    __shared__ float sN[256], sS[256];
    const int tid = threadIdx.x;
    float aN = 0.f, aS = 0.f;
    for (int r = 0; r < 64; ++r) {
        aN += stats[r * 256 + tid];
        aS += stats[16384 + r * 256 + tid];
    }
    sN[tid] = aN; sS[tid] = aS;
    __syncthreads();
    if (tid < 128) {
        const float mu = sN[tid] / (float)TN;
        const float var = sN[128 + tid] / (float)TN - mu * mu;
        const float a = bng[tid] / sqrtf(var + 1e-5f);
        prm[tid] = a;
        prm[128 + tid] = bnb[tid] - mu * a;
    } else {
        const int c = tid - 128;
        const float mu = sS[c] / (float)NSUB;
        const float var = sS[128 + c] / (float)NSUB - mu * mu;
        const float a = bnsg[c] / sqrtf(var + 1e-5f);
        prm[256 + c] = a;
        prm[384 + c] = bnsb[c] - mu * a;
    }
    for (int i = tid; i < 32768; i += 256) stats[i] = 0.f;
}

// graph pooling from XS (bf16): mean over n
__global__ void pool_kernel(const unsigned short* __restrict__ XS, float* __restrict__ hg)
{
    const int g = blockIdx.x, c = threadIdx.x;   // 128 threads
    float s = 0.f;
    for (int n = 0; n < 50; ++n)
        s += bf2f(XS[(size_t)(g * 50 + n) * 128 + c]);
    hg[g * 128 + c] = s * 0.02f;
}

__global__ void mlp_kernel(const float* __restrict__ hg,
                           const float* __restrict__ W1, const float* __restrict__ b1,
                           const float* __restrict__ W2, const float* __restrict__ b2,
                           float* __restrict__ out)
{
    __shared__ float xv[128];
    __shared__ float hid[256];
    const int g = blockIdx.x, tid = threadIdx.x;
    if (tid < 128) xv[tid] = hg[g * 128 + tid];
    __syncthreads();
    float a = b1[tid];
    for (int k = 0; k < 128; ++k) a += xv[k] * W1[k * 256 + tid];
    hid[tid] = fmaxf(a, 0.f);
    __syncthreads();
    if (tid < 10) {
        float o = b2[tid];
        for (int k = 0; k < 256; ++k) o += hid[k] * W2[k * 10 + tid];
        out[g * 10 + tid] = o;
    }
}

__global__ void zero_kernel(float* __restrict__ pz, int n)
{
    const int t = blockIdx.x * 256 + threadIdx.x;
    if (t < n) pz[t] = 0.f;
}

extern "C" void kernel_launch(void* const* d_in, const int* in_sizes, int n_in,
                              void* d_out, int out_size, void* d_ws, size_t ws_size,
                              hipStream_t stream)
{
    const float* x0   = (const float*)d_in[0];
    const float* Wr   = (const float*)d_in[1];
    const float* Wn   = (const float*)d_in[2];
    const float* bb   = (const float*)d_in[3];
    const float* bng  = (const float*)d_in[4];
    const float* bnb  = (const float*)d_in[5];
    const float* Wsr  = (const float*)d_in[6];
    const float* Wsn  = (const float*)d_in[7];
    const float* bs   = (const float*)d_in[8];
    const float* bnsg = (const float*)d_in[9];
    const float* bnsb = (const float*)d_in[10];
    const float* fW1  = (const float*)d_in[11];
    const float* fb1  = (const float*)d_in[12];
    const float* fW2  = (const float*)d_in[13];
    const float* fb2  = (const float*)d_in[14];
    const int* ei     = (const int*)d_in[15];
    const int* oei    = (const int*)d_in[16];
    float* out        = (float*)d_out;

    char* w = (char*)d_ws;
    unsigned short* A3  = (unsigned short*)w; w += (size_t)TN * 128 * 2;
    unsigned short* H1  = (unsigned short*)w; w += (size_t)TN * 128 * 2;
    unsigned short* W3T = (unsigned short*)w; w += (size_t)8 * 65536 * 2;
    unsigned short* XS  = (unsigned short*)w; w += (size_t)NSUB * 128 * 2;
    unsigned short* H2  = (unsigned short*)w; w += (size_t)NSUB * 128 * 2;
    int* rps            = (int*)w;            w += (size_t)NSUB * 51 * 4;
    unsigned char* cls  = (unsigned char*)w;  w += (size_t)NSUB * 400;
    int* rpo            = (int*)w;            w += (size_t)GG * 51 * 4;
    unsigned char* clo  = (unsigned char*)w;  w += (size_t)GG * 400;
    float* stats        = (float*)w;          w += (size_t)32768 * 4;  // [2][64][256]
    float* prm          = (float*)w;          w += 512 * 4;
    float* hg           = (float*)w;          w += (size_t)GG * 128 * 4;

    w3t_kernel<<<2048, 256, 0, stream>>>(Wr, Wn, Wsr, Wsn, W3T);
    csr_build<<<NSUB, 64, 0, stream>>>(ei, ei + 1280000, rps, cls);
    csr_build<<<GG, 64, 0, stream>>>(oei, oei + 25600, rpo, clo);
    zero_kernel<<<128, 256, 0, stream>>>(stats, 32768);
    fusexsum_kernel<false><<<NSUB, 256, 0, stream>>>(x0, nullptr, nullptr, A3, XS);

    for (int i = 0; i < NL; ++i) {
        gconv_kernel<<<TN / 100, 256, 0, stream>>>(A3, W3T + (size_t)i * 65536,
                                                   bb + i * 128, rps, cls, H1, stats);
        gconv_kernel<<<NSUB / 100, 256, 0, stream>>>(XS, W3T + (size_t)(4 + i) * 65536,
                                                     bs + i * 128, rpo, clo, H2, stats + 16384);
        bnfin_kernel<<<1, 256, 0, stream>>>(stats, bng + i * 128, bnb + i * 128,
                                            bnsg + i * 128, bnsb + i * 128, prm);
        fusexsum_kernel<true><<<NSUB, 256, 0, stream>>>(H1, H2, prm, A3, XS);
    }

    pool_kernel<<<GG, 128, 0, stream>>>(XS, hg);
    mlp_kernel<<<GG, 256, 0, stream>>>(hg, fW1, fb1, fW2, fb2, out);
}

// Round 11
// 368.052 us; speedup vs baseline: 2.8539x; 2.1555x over previous
//
#include <hip/hip_runtime.h>
#include <stdint.h>

#define D 128
#define TN 160000
#define NSUB 3200
#define GG 64
#define NL 4

typedef __bf16 bf16x8 __attribute__((ext_vector_type(8)));
typedef float f32x4 __attribute__((ext_vector_type(4)));
typedef unsigned int u32x4 __attribute__((ext_vector_type(4)));

__device__ __forceinline__ unsigned short f2bf(float v) {
    union { float f; uint32_t u; } c; c.f = v;
    uint32_t r = c.u + 0x7fffu + ((c.u >> 16) & 1u);
    return (unsigned short)(r >> 16);
}
__device__ __forceinline__ float bf2f(unsigned short h) {
    union { float f; uint32_t u; } c; c.u = ((uint32_t)h) << 16;
    return c.f;
}

__device__ __forceinline__ void gload16(const void* g, void* l) {
    __builtin_amdgcn_global_load_lds(
        (const __attribute__((address_space(1))) unsigned int*)g,
        (__attribute__((address_space(3))) unsigned int*)l, 16, 0, 0);
}

// ---------------------------------------------------------------------------
// Fused GraphConv, aggregation-as-MFMA. Block = 2 units (100 rows) x 256 cols.
// Grid 1632: blocks <1600 = node-conv (A3), >=1600 = subgraph-conv (XS).
// Main GEMM (2-term precision y = x_hi*(Whi+Wlo)): A [100][128] bf16 staged
// once (granule-XOR-swizzled), B wave-private ping-pong via global_load_lds
// (no block barriers in K-loop), m-frags per unit {0,16,32,34} (dups skipped).
// Aggregation: agg = Adj x Yn as MFMA. Adj = per-unit [50][64] bf16
// multiplicity matrix (precomputed, zero-padded, granule-swizzled); a block's
// two units are contiguous -> [2][50][64] = 6400 shorts. After the K-loop:
// waves 2,3 dump Yn TRANSPOSED bf16 -> YnT[128c][136] (16B-aligned stride);
// waves 0,1 run Adj-MFMA (C-frag layout == Yr frag layout) then
// H = Yr+agg+bias in regs, bf16 H store + BN stats -> 64-way replicas.
// ---------------------------------------------------------------------------
__global__ __launch_bounds__(256, 2)
void gconv_kernel(const unsigned short* __restrict__ A3,
                  const unsigned short* __restrict__ XS,
                  const unsigned short* __restrict__ Wt1,
                  const unsigned short* __restrict__ Wt2,
                  const float* __restrict__ bias1,
                  const float* __restrict__ bias2,
                  const unsigned short* __restrict__ AdjS,
                  const unsigned short* __restrict__ AdjO,
                  unsigned short* __restrict__ H1,
                  unsigned short* __restrict__ H2,
                  float* __restrict__ stats)
{
    __shared__ __align__(16) char lds[71680];
    // 0..25600        A [100][128] sh (swz)   -> later YnT [128][136] sh (0..34816)
    // 25600..58368    B: 4 waves x 2 x 4096B ping-pong
    // 58368..71168    Adj [2][50][64] sh (swz), +512B over-stage slack

    const int tid = threadIdx.x;
    const int blk = blockIdx.x;
    const bool big = blk < 1600;
    const int lb = big ? blk : blk - 1600;
    const unsigned short* Asrc = big ? A3 : XS;
    const unsigned short* Wt = big ? Wt1 : Wt2;
    const float* bias = big ? bias1 : bias2;
    const unsigned short* AdjG = (big ? AdjS : AdjO) + (size_t)lb * 6400;
    unsigned short* H = big ? H1 : H2;
    float* rep = stats + (big ? 0 : 16384) + (size_t)(lb & 63) * 256;
    const int rowbase = lb * 100;

    const int lane = tid & 63, wv = tid >> 6;
    const int p = lane & 15, q = lane >> 4;
    const int wn0 = wv * 64;

    // ---- phase 1: stage A (1600 granules, swz), Adj (800+slack), B0 ----
#pragma unroll
    for (int i = 0; i < 6; ++i) {
        const int c = i * 256 + tid;
        const int r = c >> 4, g = c & 15;
        gload16(Asrc + (size_t)(rowbase + r) * 128 + ((g ^ (r & 7)) << 3),
                lds + ((i * 256 + (wv << 6)) << 4));
    }
    if (wv == 0) {
        const int c = 1536 + lane;
        const int r = c >> 4, g = c & 15;
        gload16(Asrc + (size_t)(rowbase + r) * 128 + ((g ^ (r & 7)) << 3),
                lds + (1536 << 4));
    }
#pragma unroll
    for (int i = 0; i < 3; ++i) {
        const int c = i * 256 + tid;
        gload16(AdjG + (size_t)c * 8, lds + 58368 + ((i * 256 + (wv << 6)) << 4));
    }
    if (wv == 1) {   // granules 768..831 (last 32 are harmless over-stage)
        gload16(AdjG + (size_t)(768 + lane) * 8, lds + 58368 + (768 << 4));
    }
    {
        char* dst = lds + 25600 + ((wv * 2 + 0) << 12);
#pragma unroll
        for (int j = 0; j < 4; ++j)
            gload16(Wt + (size_t)wn0 * 32 + (size_t)(j * 64 + lane) * 8,
                    dst + (j << 10));
    }

    f32x4 acc[8][4];
#pragma unroll
    for (int i = 0; i < 8; ++i)
#pragma unroll
        for (int j = 0; j < 4; ++j) acc[i][j] = (f32x4){0.f, 0.f, 0.f, 0.f};

    __syncthreads();   // barrier 1

    // ---- phase 2: K-loop, 8 tiles, wave-private B ping-pong ----
    static const int FR[8] = {0, 16, 32, 34, 50, 66, 82, 84};
    const unsigned short* Ash = (const unsigned short*)lds;
#pragma unroll
    for (int t = 0; t < 8; ++t) {
        if (t > 0) asm volatile("s_waitcnt vmcnt(0)" ::: "memory");
        const unsigned short* Bw =
            (const unsigned short*)(lds + 25600 + ((wv * 2 + (t & 1)) << 12));
        bf16x8 bfr[4];
#pragma unroll
        for (int ni = 0; ni < 4; ++ni) {
            u32x4 raw = *(const u32x4*)&Bw[(ni * 16 + p) * 32 + q * 8];
            bfr[ni] = __builtin_bit_cast(bf16x8, raw);
        }
        if (t < 7) {
            char* dst = lds + 25600 + ((wv * 2 + ((t + 1) & 1)) << 12);
#pragma unroll
            for (int j = 0; j < 4; ++j)
                gload16(Wt + ((size_t)(t + 1) << 13) + (size_t)wn0 * 32 +
                            (size_t)(j * 64 + lane) * 8,
                        dst + (j << 10));
        }
        const int gb = (t & 3) * 4 + q;
        __builtin_amdgcn_s_setprio(1);
#pragma unroll
        for (int mi = 0; mi < 8; ++mi) {
            const int rr = FR[mi] + p;
            u32x4 raw = *(const u32x4*)&Ash[rr * 128 + ((gb ^ (rr & 7)) << 3)];
            bf16x8 afr = __builtin_bit_cast(bf16x8, raw);
#pragma unroll
            for (int ni = 0; ni < 4; ++ni)
                acc[mi][ni] = __builtin_amdgcn_mfma_f32_16x16x32_bf16(afr, bfr[ni], acc[mi][ni], 0, 0, 0);
        }
        __builtin_amdgcn_s_setprio(0);
    }

    __syncthreads();   // barrier 2: all A/B reads done; A+B region reusable

    // ---- phase 3: waves 2,3 dump YnT (bf16, transposed); waves 0,1 zero pad
    static const int F4[4] = {0, 16, 32, 34};
    unsigned short* YnT = (unsigned short*)lds;
    if (wv >= 2) {
        const int cb = (wv - 2) * 64;
#pragma unroll
        for (int u = 0; u < 2; ++u)
#pragma unroll
            for (int fi = 0; fi < 4; ++fi) {
#pragma unroll
                for (int rp = 0; rp < 4; rp += 2) {
                    if (fi == 3 && (q * 4 + rp) < 14) continue;
                    const int jl = F4[fi] + q * 4 + rp;
#pragma unroll
                    for (int ni = 0; ni < 4; ++ni) {
                        const int c = cb + ni * 16 + p;
                        const uint32_t v =
                            (uint32_t)f2bf(acc[u * 4 + fi][ni][rp]) |
                            ((uint32_t)f2bf(acc[u * 4 + fi][ni][rp + 1]) << 16);
                        *(uint32_t*)&YnT[c * 136 + u * 64 + jl] = v;
                    }
                }
            }
    } else {
        const int c = wv * 64 + lane;   // 128 threads cover all cols
#pragma unroll
        for (int u = 0; u < 2; ++u)
#pragma unroll
            for (int k = 0; k < 7; ++k)
                *(uint32_t*)&YnT[c * 136 + u * 64 + 50 + k * 2] = 0;
    }
    __syncthreads();   // barrier 3

    // ---- phase 4: waves 0,1: agg = Adj x YnT (MFMA), H = Yr+agg+bias ----
    if (wv < 2) {
        const int cb = wv * 64;
        const unsigned short* AdjL = (const unsigned short*)(lds + 58368);
        float sm[4] = {0.f, 0.f, 0.f, 0.f}, sq[4] = {0.f, 0.f, 0.f, 0.f};
        float bv[4];
#pragma unroll
        for (int ni = 0; ni < 4; ++ni) bv[ni] = bias[cb + ni * 16 + p];
#pragma unroll
        for (int u = 0; u < 2; ++u) {
            f32x4 aacc[4][4];
#pragma unroll
            for (int i = 0; i < 4; ++i)
#pragma unroll
                for (int j = 0; j < 4; ++j) aacc[i][j] = (f32x4){0.f, 0.f, 0.f, 0.f};
#pragma unroll
            for (int ks = 0; ks < 2; ++ks) {
                bf16x8 afr[4], bfr2[4];
#pragma unroll
                for (int fi = 0; fi < 4; ++fi) {
                    const int m = F4[fi] + p;
                    const int gi = ks * 4 + q;
                    u32x4 raw = *(const u32x4*)&AdjL[(u * 50 + m) * 64 + ((gi ^ (m & 7)) << 3)];
                    afr[fi] = __builtin_bit_cast(bf16x8, raw);
                }
#pragma unroll
                for (int ni = 0; ni < 4; ++ni) {
                    u32x4 raw = *(const u32x4*)&YnT[(cb + ni * 16 + p) * 136 + u * 64 + ks * 32 + q * 8];
                    bfr2[ni] = __builtin_bit_cast(bf16x8, raw);
                }
#pragma unroll
                for (int fi = 0; fi < 4; ++fi)
#pragma unroll
                    for (int ni = 0; ni < 4; ++ni)
                        aacc[fi][ni] = __builtin_amdgcn_mfma_f32_16x16x32_bf16(afr[fi], bfr2[ni], aacc[fi][ni], 0, 0, 0);
            }
#pragma unroll
            for (int fi = 0; fi < 4; ++fi)
#pragma unroll
                for (int r = 0; r < 4; ++r) {
                    if (fi == 3 && (q * 4 + r) < 14) continue;
                    const int row = u * 50 + F4[fi] + q * 4 + r;
#pragma unroll
                    for (int ni = 0; ni < 4; ++ni) {
                        const int cc = cb + ni * 16 + p;
                        const float h = acc[u * 4 + fi][ni][r] + aacc[fi][ni][r] + bv[ni];
                        H[(size_t)(rowbase + row) * 128 + cc] = f2bf(h);
                        sm[ni] += h; sq[ni] += h * h;
                    }
                }
        }
#pragma unroll
        for (int ni = 0; ni < 4; ++ni) {
            atomicAdd(&rep[cb + ni * 16 + p], sm[ni]);
            atomicAdd(&rep[128 + cb + ni * 16 + p], sq[ni]);
        }
    }
}

// ---------------------------------------------------------------------------
// adj_build: one block per unit. Dense [50][64] multiplicity matrix in LDS,
// written out bf16 ([50][64] = 3200 shorts per unit, contiguous across units)
// with the gconv granule swizzle pre-applied.
// ---------------------------------------------------------------------------
__global__ void adj_build(const int* __restrict__ src, const int* __restrict__ dst,
                          unsigned short* __restrict__ AdjG)
{
    __shared__ int cnt[3200];
    const int u = blockIdx.x, t = threadIdx.x;
    for (int i = t; i < 3200; i += 256) cnt[i] = 0;
    __syncthreads();
    for (int e = t; e < 400; e += 256) {
        const int d = dst[u * 400 + e] - u * 50;
        const int s = src[u * 400 + e] - u * 50;
        atomicAdd(&cnt[d * 64 + s], 1);
    }
    __syncthreads();
    for (int i = t; i < 3200; i += 256) {
        const int m = i >> 6, j = i & 63;
        const float v = (float)cnt[i];
        const int pos = m * 64 + ((((j >> 3) ^ (m & 7)) << 3) | (j & 7));
        AdjG[(size_t)u * 3200 + pos] = f2bf(v);
    }
}

// ---------------------------------------------------------------------------
// fuse (BN1+BN2[node_idx]+relu) + bf16 -> A3 (hi only), subgraph-mean -> XS.
// ---------------------------------------------------------------------------
template <bool FUSE>
__global__ __launch_bounds__(256)
void fusexsum_kernel(const void* __restrict__ HPv,
                     const unsigned short* __restrict__ H2,
                     const float* __restrict__ prm,
                     unsigned short* __restrict__ A3,
                     unsigned short* __restrict__ XS)
{
    __shared__ float red[256];
    const unsigned short* HPb = (const unsigned short*)HPv;
    const float* HPf = (const float*)HPv;
    const int blk = blockIdx.x;          // g*50 + n
    const int g = blk / 50, n = blk - g * 50;
    const int tid = threadIdx.x;
    const int c = tid & 127, sh = tid >> 7;
    float a1 = 0.f, c1 = 0.f, hh = 0.f;
    if (FUSE) {
        a1 = prm[c]; c1 = prm[128 + c];
        const float a2 = prm[256 + c], c2 = prm[384 + c];
        hh = a2 * bf2f(H2[(size_t)blk * 128 + c]) + c2;
    }
    float accum = 0.f;
    const int s0 = sh * 25;
    for (int s = s0; s < s0 + 25; ++s) {
        const size_t row = (size_t)g * 2500 + s * 50 + n;
        float v = FUSE ? bf2f(HPb[row * 128 + c]) : HPf[row * 128 + c];
        if (FUSE) v = fmaxf(0.f, a1 * v + c1 + hh);
        A3[row * 128 + c] = f2bf(v);
        accum += v;
    }
    red[tid] = accum;
    __syncthreads();
    if (tid < 128) {
        const float xv = (red[tid] + red[tid + 128]) * 0.02f;
        XS[(size_t)blk * 128 + c] = f2bf(xv);
    }
}

// build W3T: 8 matrices x 8 tiles x [256 n][32 k] bf16; tiles 0-3 = hi(W),
// tiles 4-7 = lo(W) k-slices.
__global__ void w3t_kernel(const float* __restrict__ Wr, const float* __restrict__ Wn,
                           const float* __restrict__ Wsr, const float* __restrict__ Wsn,
                           unsigned short* __restrict__ W3T)
{
    const int idx = blockIdx.x * 256 + threadIdx.x;  // 8*65536
    const int m = idx >> 16;
    const int r = idx & 65535;
    const int bt = r >> 13;
    const int rr = r & 8191;
    const int n = rr >> 5, kloc = rr & 31;
    const int kg = (bt & 3) * 32 + kloc;
    const float* Wa = (m < 4) ? Wr + (size_t)m * 16384 : Wsr + (size_t)(m - 4) * 16384;
    const float* Wb = (m < 4) ? Wn + (size_t)m * 16384 : Wsn + (size_t)(m - 4) * 16384;
    const float w = (n < 128) ? Wa[kg * 128 + n] : Wb[kg * 128 + (n - 128)];
    const unsigned short hi = f2bf(w);
    W3T[idx] = (bt < 4) ? hi : f2bf(w - bf2f(hi));
}

// finalize BN params from 64-replica stats; prm = [a1,c1,a2,c2]; re-zero reps
__global__ void bnfin_kernel(float* __restrict__ stats,
                             const float* __restrict__ bng, const float* __restrict__ bnb,
                             const float* __restrict__ bnsg, const float* __restrict__ bnsb,
                             float* __restrict__ prm)
{
    __shared__ float sN[256], sS[256];
    const int tid = threadIdx.x;
    float aN = 0.f, aS = 0.f;
    for (int r = 0; r < 64; ++r) {
        aN += stats[r * 256 + tid];
        aS += stats[16384 + r * 256 + tid];
    }
    sN[tid] = aN; sS[tid] = aS;
    __syncthreads();
    if (tid < 128) {
        const float mu = sN[tid] / (float)TN;
        const float var = sN[128 + tid] / (float)TN - mu * mu;
        const float a = bng[tid] / sqrtf(var + 1e-5f);
        prm[tid] = a;
        prm[128 + tid] = bnb[tid] - mu * a;
    } else {
        const int c = tid - 128;
        const float mu = sS[c] / (float)NSUB;
        const float var = sS[128 + c] / (float)NSUB - mu * mu;
        const float a = bnsg[c] / sqrtf(var + 1e-5f);
        prm[256 + c] = a;
        prm[384 + c] = bnsb[c] - mu * a;
    }
    for (int i = tid; i < 32768; i += 256) stats[i] = 0.f;
}

// graph pooling from XS (bf16): mean over n
__global__ void pool_kernel(const unsigned short* __restrict__ XS, float* __restrict__ hg)
{
    const int g = blockIdx.x, c = threadIdx.x;   // 128 threads
    float s = 0.f;
    for (int n = 0; n < 50; ++n)
        s += bf2f(XS[(size_t)(g * 50 + n) * 128 + c]);
    hg[g * 128 + c] = s * 0.02f;
}

__global__ void mlp_kernel(const float* __restrict__ hg,
                           const float* __restrict__ W1, const float* __restrict__ b1,
                           const float* __restrict__ W2, const float* __restrict__ b2,
                           float* __restrict__ out)
{
    __shared__ float xv[128];
    __shared__ float hid[256];
    const int g = blockIdx.x, tid = threadIdx.x;
    if (tid < 128) xv[tid] = hg[g * 128 + tid];
    __syncthreads();
    float a = b1[tid];
    for (int k = 0; k < 128; ++k) a += xv[k] * W1[k * 256 + tid];
    hid[tid] = fmaxf(a, 0.f);
    __syncthreads();
    if (tid < 10) {
        float o = b2[tid];
        for (int k = 0; k < 256; ++k) o += hid[k] * W2[k * 10 + tid];
        out[g * 10 + tid] = o;
    }
}

__global__ void zero_kernel(float* __restrict__ pz, int n)
{
    const int t = blockIdx.x * 256 + threadIdx.x;
    if (t < n) pz[t] = 0.f;
}

extern "C" void kernel_launch(void* const* d_in, const int* in_sizes, int n_in,
                              void* d_out, int out_size, void* d_ws, size_t ws_size,
                              hipStream_t stream)
{
    const float* x0   = (const float*)d_in[0];
    const float* Wr   = (const float*)d_in[1];
    const float* Wn   = (const float*)d_in[2];
    const float* bb   = (const float*)d_in[3];
    const float* bng  = (const float*)d_in[4];
    const float* bnb  = (const float*)d_in[5];
    const float* Wsr  = (const float*)d_in[6];
    const float* Wsn  = (const float*)d_in[7];
    const float* bs   = (const float*)d_in[8];
    const float* bnsg = (const float*)d_in[9];
    const float* bnsb = (const float*)d_in[10];
    const float* fW1  = (const float*)d_in[11];
    const float* fb1  = (const float*)d_in[12];
    const float* fW2  = (const float*)d_in[13];
    const float* fb2  = (const float*)d_in[14];
    const int* ei     = (const int*)d_in[15];
    const int* oei    = (const int*)d_in[16];
    float* out        = (float*)d_out;

    char* w = (char*)d_ws;
    unsigned short* A3  = (unsigned short*)w; w += (size_t)TN * 128 * 2;
    unsigned short* H1  = (unsigned short*)w; w += (size_t)TN * 128 * 2;
    unsigned short* W3T = (unsigned short*)w; w += (size_t)8 * 65536 * 2;
    unsigned short* XS  = (unsigned short*)w; w += (size_t)NSUB * 128 * 2;
    unsigned short* H2  = (unsigned short*)w; w += (size_t)NSUB * 128 * 2;
    unsigned short* AdjS = (unsigned short*)w; w += (size_t)NSUB * 3200 * 2;
    unsigned short* AdjO = (unsigned short*)w; w += (size_t)GG * 3200 * 2 + 4096;
    float* stats        = (float*)w;          w += (size_t)32768 * 4;  // [2][64][256]
    float* prm          = (float*)w;          w += 512 * 4;
    float* hg           = (float*)w;          w += (size_t)GG * 128 * 4;

    w3t_kernel<<<2048, 256, 0, stream>>>(Wr, Wn, Wsr, Wsn, W3T);
    adj_build<<<NSUB, 256, 0, stream>>>(ei, ei + 1280000, AdjS);
    adj_build<<<GG, 256, 0, stream>>>(oei, oei + 25600, AdjO);
    zero_kernel<<<128, 256, 0, stream>>>(stats, 32768);
    fusexsum_kernel<false><<<NSUB, 256, 0, stream>>>(x0, nullptr, nullptr, A3, XS);

    for (int i = 0; i < NL; ++i) {
        gconv_kernel<<<1632, 256, 0, stream>>>(A3, XS,
                                               W3T + (size_t)i * 65536,
                                               W3T + (size_t)(4 + i) * 65536,
                                               bb + i * 128, bs + i * 128,
                                               AdjS, AdjO, H1, H2, stats);
        bnfin_kernel<<<1, 256, 0, stream>>>(stats, bng + i * 128, bnb + i * 128,
                                            bnsg + i * 128, bnsb + i * 128, prm);
        fusexsum_kernel<true><<<NSUB, 256, 0, stream>>>(H1, H2, prm, A3, XS);
    }

    pool_kernel<<<GG, 128, 0, stream>>>(XS, hg);
    mlp_kernel<<<GG, 256, 0, stream>>>(hg, fW1, fb1, fW2, fb2, out);
}